// Round 4
// baseline (422.129 us; speedup 1.0000x reference)
//
#include <hip/hip_runtime.h>
#include <math.h>

// HPool: z[n,c] = sum_hw tanh(x[n,c,hw]) * coeff[c, bin(x[n,c,hw])]
// bins = linspace(global_min, global_max, 33), searchsorted-right, clip [0,31].
//
// R10: R9 with ONE variable changed -- pass2 geometry back to 256 threads,
// VGPR pinned <=64 via __launch_bounds__(256,8) => 8 waves/SIMD (full 32
// waves/CU), keeping 8 global_load_dwordx4 in flight via a hand-unrolled
// a/b register pipeline (static names, no runtime-indexed array -> no
// scratch). R9's 512-thr + buf[8] pushed VGPR past 64 and halved occupancy
// (8->4 waves/SIMD quantum), costing +13us vs R6.
//
// Accounting model (R6/R7/R9 consistent): timed region = 2 harness poison
// fills (~321us, not ours) + pass1 + pass2. Floor: pass1 = 268MB @ 6.3TB/s
// ~= 43us (HBM, irreducible: bin edges need global min/max); pass2 = 268MB
// from L3 (proven by R7 FETCH=247MiB; x == L3 size) ~= 40us. R6 hit ~82us
// kernel time; R9 ~95us.
//
// Lessons: R3/R4 scattered LDS atomics dead; R5: coeff gather not the
// bottleneck; R6/R7: pass-2 re-read is L3-hit regardless of order; R7:
// cooperative co-residency caps occupancy -- don't fuse; R9: >64 VGPR
// halves occupancy -- pin it.
//
// Shapes: N=64, C=64, HW=16384, BINS=32. x = 256 MiB fp32.

constexpr int NB1  = 2048;   // pass-1 blocks (8/CU)
constexpr int BT1  = 256;    // pass-1 threads/block
constexpr int BT2  = 256;    // pass-2 threads/block (4 waves)
constexpr int BINS = 32;

__device__ __forceinline__ float wave_min(float v) {
#pragma unroll
    for (int off = 32; off > 0; off >>= 1) v = fminf(v, __shfl_down(v, off, 64));
    return v;
}
__device__ __forceinline__ float wave_max(float v) {
#pragma unroll
    for (int off = 32; off > 0; off >>= 1) v = fmaxf(v, __shfl_down(v, off, 64));
    return v;
}
__device__ __forceinline__ float wave_sum(float v) {
#pragma unroll
    for (int off = 32; off > 0; off >>= 1) v += __shfl_down(v, off, 64);
    return v;
}

// ---------------- pass 1: grid-stride min/max partials ----------------
__global__ __launch_bounds__(BT1) void minmax_partial(
    const float4* __restrict__ x4, int n4, float2* __restrict__ pmm) {
    const int tid    = blockIdx.x * BT1 + threadIdx.x;
    const int stride = NB1 * BT1;            // 524,288 float4 = 8 MiB sweep
    const int iters  = n4 / stride;          // 32 for the fixed shapes
    float vmin0 = INFINITY, vmax0 = -INFINITY;
    float vmin1 = INFINITY, vmax1 = -INFINITY;
#pragma unroll 8
    for (int k = 0; k < iters; ++k) {
        float4 v = x4[tid + k * stride];
        vmin0 = fminf(vmin0, fminf(v.x, v.y));
        vmax0 = fmaxf(vmax0, fmaxf(v.x, v.y));
        vmin1 = fminf(vmin1, fminf(v.z, v.w));
        vmax1 = fmaxf(vmax1, fmaxf(v.z, v.w));
    }
    for (int i = tid + iters * stride; i < n4; i += stride) {   // shape tail
        float4 v = x4[i];
        vmin0 = fminf(vmin0, fminf(v.x, v.y));
        vmax0 = fmaxf(vmax0, fmaxf(v.x, v.y));
        vmin1 = fminf(vmin1, fminf(v.z, v.w));
        vmax1 = fmaxf(vmax1, fmaxf(v.z, v.w));
    }
    float vmin = fminf(vmin0, vmin1), vmax = fmaxf(vmax0, vmax1);
    __shared__ float smin[4], smax[4];
    const int lane = threadIdx.x & 63, wave = threadIdx.x >> 6;
    vmin = wave_min(vmin);
    vmax = wave_max(vmax);
    if (lane == 0) { smin[wave] = vmin; smax[wave] = vmax; }
    __syncthreads();
    if (threadIdx.x == 0) {
        pmm[blockIdx.x] = make_float2(
            fminf(fminf(smin[0], smin[1]), fminf(smin[2], smin[3])),
            fmaxf(fmaxf(smax[0], smax[1]), fmaxf(smax[2], smax[3])));
    }
}

// ------------- pass 2: fused pmm-reduce + main kernel, 256 thr -------------
__global__ __launch_bounds__(BT2, 8) void hpool_main(
    const float* __restrict__ x, const float* __restrict__ coeff,
    const float2* __restrict__ pmm, float* __restrict__ out,
    int C, int hw4, int nc_total) {
    __shared__ float smin[4], smax[4], s_red[4];
    __shared__ float s_par[2];                 // 4*inv_step, 4*(-min*inv_step)
    const int t    = threadIdx.x;
    const int nc   = blockIdx.x;
    const int c    = nc % C;
    const int lane = t & 63, wave = t >> 6;

    // per-lane coeff fragment: lane j holds coeff[c, j&31] (wave-replicated)
    const float cf = coeff[c * BINS + (lane & (BINS - 1))];

    // prologue: every block reduces the 2048 partials (L2/L3-hot, 16 KiB)
    float vmin = INFINITY, vmax = -INFINITY;
#pragma unroll
    for (int k = t; k < NB1; k += BT2) {       // 8 iters
        float2 mm = pmm[k];
        vmin = fminf(vmin, mm.x);
        vmax = fmaxf(vmax, mm.y);
    }
    vmin = wave_min(vmin);
    vmax = wave_max(vmax);
    if (lane == 0) { smin[wave] = vmin; smax[wave] = vmax; }
    __syncthreads();
    if (t == 0) {
        float m = fminf(fminf(smin[0], smin[1]), fminf(smin[2], smin[3]));
        float M = fmaxf(fmaxf(smax[0], smax[1]), fmaxf(smax[2], smax[3]));
        float step = (M - m) / (float)BINS;
        float inv  = 1.0f / step;
        s_par[0] = 4.0f * inv;                 // byte-space binning: idx4 = 4*idx
        s_par[1] = 4.0f * (-m * inv);
    }
    __syncthreads();
    const float inv4 = s_par[0];
    const float nmi4 = s_par[1];

    const float4* base = (const float4*)x + (size_t)nc * hw4;
    float acc0 = 0.0f, acc1 = 0.0f;

    auto contrib = [&](float v) -> float {
        // byte-space bin: floor(4*sc)&~3 == 4*floor(sc) for sc>=0; feeds
        // ds_bpermute's byte-addressed lane select without an extra shift.
        float sc4 = fmaf(v, inv4, nmi4);
        int  idx4 = (int)sc4;
        idx4 = idx4 > 4 * (BINS - 1) ? 4 * (BINS - 1) : (idx4 & ~3);
        float w   = __builtin_bit_cast(float,
                      __builtin_amdgcn_ds_bpermute(idx4, __builtin_bit_cast(int, cf)));
        float e   = __expf(2.0f * v);          // |2v| < ~12, no overflow
        float th  = fmaf(-2.0f, __frcp_rn(e + 1.0f), 1.0f);  // tanh(v)
        return th * w;
    };
    auto quad = [&](float4 v) {
        acc0 += contrib(v.x);
        acc1 += contrib(v.y);
        acc0 += contrib(v.z);
        acc1 += contrib(v.w);
    };

    if (hw4 == 16 * BT2) {
        // fixed-shape fast path: row = 16 float4/thread. Hand-unrolled a/b
        // register pipeline: 8 loads issued before first use, refill groups
        // of 4 while the other 4 compute. Static names only (rule: runtime-
        // indexed arrays -> scratch). 8 x float4 = 32 VGPR buffer.
        float4 a0 = base[t +  0 * BT2], a1 = base[t +  1 * BT2],
               a2 = base[t +  2 * BT2], a3 = base[t +  3 * BT2];
        float4 b0 = base[t +  4 * BT2], b1 = base[t +  5 * BT2],
               b2 = base[t +  6 * BT2], b3 = base[t +  7 * BT2];
        quad(a0); quad(a1); quad(a2); quad(a3);
        a0 = base[t +  8 * BT2]; a1 = base[t +  9 * BT2];
        a2 = base[t + 10 * BT2]; a3 = base[t + 11 * BT2];
        quad(b0); quad(b1); quad(b2); quad(b3);
        b0 = base[t + 12 * BT2]; b1 = base[t + 13 * BT2];
        b2 = base[t + 14 * BT2]; b3 = base[t + 15 * BT2];
        quad(a0); quad(a1); quad(a2); quad(a3);
        quad(b0); quad(b1); quad(b2); quad(b3);
    } else {
        // generic path (robust to shape changes)
        for (int i = t; i < hw4; i += BT2) quad(base[i]);
    }

    float acc = wave_sum(acc0 + acc1);
    if (lane == 0) s_red[wave] = acc;
    __syncthreads();
    if (t == 0) out[nc] = (s_red[0] + s_red[1]) + (s_red[2] + s_red[3]);
}

extern "C" void kernel_launch(void* const* d_in, const int* in_sizes, int n_in,
                              void* d_out, int out_size, void* d_ws, size_t ws_size,
                              hipStream_t stream) {
    const float* x     = (const float*)d_in[0];
    const float* coeff = (const float*)d_in[1];
    float*  out = (float*)d_out;
    float2* pmm = (float2*)d_ws;               // NB1 float2 = 16 KiB

    const int total = in_sizes[0];             // 67,108,864 elements
    const int n4    = total / 4;
    const int C     = in_sizes[1] / BINS;      // 64
    const int NC    = out_size;                // 4096
    const int hw4   = total / NC / 4;          // 4096 float4 per (n,c)

    minmax_partial<<<NB1, BT1, 0, stream>>>((const float4*)x, n4, pmm);
    hpool_main<<<NC, BT2, 0, stream>>>(x, coeff, pmm, out, C, hw4, NC);
}

// Round 5
// 402.723 us; speedup vs baseline: 1.0482x; 1.0482x over previous
//
#include <hip/hip_runtime.h>
#include <math.h>

// HPool: z[n,c] = sum_hw tanh(x[n,c,hw]) * coeff[c, bin(x[n,c,hw])]
// bins = linspace(global_min, global_max, 33), searchsorted-right, clip [0,31].
//
// R11 == R6 restored byte-identical (best measured: 402.9us). R7-R10 all
// regressed; attribution:
//   R7  (688): cooperative fusion capped occupancy at 16 waves/CU; proved
//              pass2 is L3-served (FETCH ~= 247MiB = ONE HBM pass of x).
//   R9  (416): pass1 contiguous->grid-stride (+~13us) + 512-thr hoisted
//              pass2 (>64 VGPR halves the wave quantum).
//   R10 (422): same grid-stride pass1; hand a/b pipeline no better --
//              compiler schedules R6's plain unroll-4 loop best.
//
// Refined floor model: timed iter = 1GiB poison fill (~160us) + fixed
// overhead (R7 calibration: ~268us total fill+gaps) + kernels (~135us).
// The fill leaves ~256MiB DIRTY in L3; pass1's streaming read must evict
// it -> pass1 ~= 268MB read + 256MB writeback ~= 83us (not 43). pass2
// L3-served ~= 25-45us. Kernel floor ~= 110-125us vs measured ~135us:
// <10% kernel headroom, ~3% of dur_us. Three attempts to grab it cost
// 13-19us each. This structure is the empirical optimum.
//
// Lessons: R3/R4 scattered LDS atomics dead; R5: coeff gather not the
// bottleneck; R6/R7: pass-2 re-read is L3-hit regardless of order; R7:
// don't fuse; R9: keep VGPR <=64; R9/R10: keep pass1 contiguous, keep
// pass2's simple loop.
//
// Shapes: N=64, C=64, HW=16384, BINS=32. x = 256 MiB fp32.

constexpr int NB1  = 2048;   // pass-1 blocks
constexpr int BT   = 256;    // threads/block
constexpr int BINS = 32;

__device__ __forceinline__ float wave_min(float v) {
#pragma unroll
    for (int off = 32; off > 0; off >>= 1) v = fminf(v, __shfl_down(v, off, 64));
    return v;
}
__device__ __forceinline__ float wave_max(float v) {
#pragma unroll
    for (int off = 32; off > 0; off >>= 1) v = fmaxf(v, __shfl_down(v, off, 64));
    return v;
}
__device__ __forceinline__ float wave_sum(float v) {
#pragma unroll
    for (int off = 32; off > 0; off >>= 1) v += __shfl_down(v, off, 64);
    return v;
}

// ------- pass 1: contiguous per-block min/max partials -------
__global__ __launch_bounds__(BT) void minmax_partial(
    const float4* __restrict__ x4, int n4, float2* __restrict__ pmm) {
    const int per = n4 / NB1;                 // 8192 float4 per block
    const int i0  = blockIdx.x * per + threadIdx.x;
    const int iters = per / BT;               // 32
    float vmin = INFINITY, vmax = -INFINITY;
#pragma unroll 4
    for (int k = 0; k < iters; ++k) {
        float4 v = x4[i0 + k * BT];
        vmin = fminf(vmin, fminf(fminf(v.x, v.y), fminf(v.z, v.w)));
        vmax = fmaxf(vmax, fmaxf(fmaxf(v.x, v.y), fmaxf(v.z, v.w)));
    }
    // tail (robust to shape changes; empty for the fixed shapes)
    for (int r = NB1 * per + blockIdx.x * BT + threadIdx.x; r < n4; r += NB1 * BT) {
        float4 v = x4[r];
        vmin = fminf(vmin, fminf(fminf(v.x, v.y), fminf(v.z, v.w)));
        vmax = fmaxf(vmax, fmaxf(fmaxf(v.x, v.y), fmaxf(v.z, v.w)));
    }
    __shared__ float smin[4], smax[4];
    const int lane = threadIdx.x & 63, wave = threadIdx.x >> 6;
    vmin = wave_min(vmin);
    vmax = wave_max(vmax);
    if (lane == 0) { smin[wave] = vmin; smax[wave] = vmax; }
    __syncthreads();
    if (threadIdx.x == 0) {
        pmm[blockIdx.x] = make_float2(
            fminf(fminf(smin[0], smin[1]), fminf(smin[2], smin[3])),
            fmaxf(fmaxf(smax[0], smax[1]), fmaxf(smax[2], smax[3])));
    }
}

// ---------------- pass 2: fused reduce + main kernel (reversed) ----------------
__global__ __launch_bounds__(BT) void hpool_main(
    const float* __restrict__ x, const float* __restrict__ coeff,
    const float2* __restrict__ pmm, float* __restrict__ out,
    int C, int hw4, int nc_total) {
    __shared__ float smin[4], smax[4], s_red[4];
    __shared__ float s_par[2];                 // 4*inv_step, 4*(-min*inv_step)
    const int t    = threadIdx.x;
    const int nc   = nc_total - 1 - blockIdx.x;   // reversed dispatch order
    const int c    = nc % C;
    const int lane = t & 63, wave = t >> 6;

    // per-lane coeff fragment: lane j holds coeff[c, j&31] (wave-replicated)
    const float cf = coeff[c * BINS + (lane & (BINS - 1))];

    // prologue: every block reduces the 2048 partials (L2-hot, 16 KiB)
    float vmin = INFINITY, vmax = -INFINITY;
#pragma unroll
    for (int k = t; k < NB1; k += BT) {
        float2 mm = pmm[k];
        vmin = fminf(vmin, mm.x);
        vmax = fmaxf(vmax, mm.y);
    }
    vmin = wave_min(vmin);
    vmax = wave_max(vmax);
    if (lane == 0) { smin[wave] = vmin; smax[wave] = vmax; }
    __syncthreads();
    if (t == 0) {
        float m = fminf(fminf(smin[0], smin[1]), fminf(smin[2], smin[3]));
        float M = fmaxf(fmaxf(smax[0], smax[1]), fmaxf(smax[2], smax[3]));
        float step = (M - m) / (float)BINS;
        float inv  = 1.0f / step;
        s_par[0] = 4.0f * inv;                 // byte-space binning: idx4 = 4*idx
        s_par[1] = 4.0f * (-m * inv);
    }
    __syncthreads();
    const float inv4 = s_par[0];
    const float nmi4 = s_par[1];

    const float4* base = (const float4*)x + (size_t)nc * hw4;
    float acc0 = 0.0f, acc1 = 0.0f;
    const int iters = hw4 / BT;                // 16 for the fixed shapes

    auto contrib = [&](float v) -> float {
        // byte-space bin: floor(4*sc)&~3 == 4*floor(sc) for sc>=0; feeds
        // ds_bpermute's byte-addressed lane select without an extra shift.
        float sc4 = fmaf(v, inv4, nmi4);
        int  idx4 = (int)sc4;
        idx4 = idx4 > 4 * (BINS - 1) ? 4 * (BINS - 1) : (idx4 & ~3);
        float w   = __builtin_bit_cast(float,
                      __builtin_amdgcn_ds_bpermute(idx4, __builtin_bit_cast(int, cf)));
        float e   = __expf(2.0f * v);          // |2v| < ~12, no overflow
        float th  = fmaf(-2.0f, __frcp_rn(e + 1.0f), 1.0f);  // tanh(v)
        return th * w;
    };

#pragma unroll 4
    for (int k = 0; k < iters; ++k) {
        float4 v = base[t + BT * k];
        acc0 += contrib(v.x);
        acc1 += contrib(v.y);
        acc0 += contrib(v.z);
        acc1 += contrib(v.w);
    }
    float acc = wave_sum(acc0 + acc1);
    if (lane == 0) s_red[wave] = acc;
    __syncthreads();
    if (t == 0) out[nc] = s_red[0] + s_red[1] + s_red[2] + s_red[3];
}

extern "C" void kernel_launch(void* const* d_in, const int* in_sizes, int n_in,
                              void* d_out, int out_size, void* d_ws, size_t ws_size,
                              hipStream_t stream) {
    const float* x     = (const float*)d_in[0];
    const float* coeff = (const float*)d_in[1];
    float*  out = (float*)d_out;
    float2* pmm = (float2*)d_ws;               // NB1 float2 = 16 KiB

    const int total = in_sizes[0];             // 67,108,864
    const int n4    = total / 4;
    const int C     = in_sizes[1] / BINS;      // 64
    const int NC    = out_size;                // 4096
    const int hw4   = total / NC / 4;          // 4096 float4 per (n,c)

    minmax_partial<<<NB1, BT, 0, stream>>>((const float4*)x, n4, pmm);
    hpool_main<<<NC, BT, 0, stream>>>(x, coeff, pmm, out, C, hw4, NC);
}